// Round 9
// baseline (341.739 us; speedup 1.0000x reference)
//
#include <hip/hip_runtime.h>
#include <hip/hip_bf16.h>
#include <stdint.h>

#define M_DIM 8192   // 4*2048
#define N_DIM 4096   // OUT_FEATURES
#define K_DIM 4096   // IN_FEATURES
#define KB2   (K_DIM * 2)   // bytes per K-row

typedef __attribute__((ext_vector_type(8))) __bf16 bf16x8;
typedef __attribute__((ext_vector_type(4))) float  f32x4;

#define GLD_LDS16(gaddr, laddr)                                            \
  __builtin_amdgcn_global_load_lds(                                        \
      (const __attribute__((address_space(1))) uint32_t*)(gaddr),          \
      (__attribute__((address_space(3))) uint32_t*)(laddr), 16, 0, 0)

// ---------------------------------------------------------------------------
// Dequant: qweight (8, O, 128) int32 bit-planes + lut (O,16) -> Wb (O,K) bf16
// ---------------------------------------------------------------------------
__global__ __launch_bounds__(256) void anyprec_dequant_kernel(
    const int* __restrict__ q, const float* __restrict__ lut,
    __bf16* __restrict__ Wb) {
  int t = blockIdx.x * 256 + threadIdx.x;   // 0 .. O*128-1
  int o = t >> 7;
  int w = t & 127;
  const int PLANE = N_DIM * (K_DIM / 32);
  int base = o * (K_DIM / 32) + w;
  uint32_t q0 = (uint32_t)q[0 * PLANE + base];
  uint32_t q1 = (uint32_t)q[1 * PLANE + base];
  uint32_t q2 = (uint32_t)q[2 * PLANE + base];
  uint32_t q3 = (uint32_t)q[3 * PLANE + base];
  const float* lrow = lut + o * 16;

  __bf16 vals[32];
#pragma unroll
  for (int i = 0; i < 32; ++i) {
    uint32_t idx = ((q0 >> i) & 1u) | (((q1 >> i) & 1u) << 1) |
                   (((q2 >> i) & 1u) << 2) | (((q3 >> i) & 1u) << 3);
    vals[i] = (__bf16)lrow[idx];
  }
  bf16x8* dst = (bf16x8*)(Wb + (size_t)o * K_DIM + w * 32);
#pragma unroll
  for (int r = 0; r < 4; ++r) {
    bf16x8 v;
#pragma unroll
    for (int j = 0; j < 8; ++j) v[j] = vals[r * 8 + j];
    dst[r] = v;
  }
}

// ---------------------------------------------------------------------------
// x fp32 -> bf16 in FRAGMENT-MAJOR layout:
// frag id f = m16*128 + kt*2 + ks  (m16=row/16, kt=K-tile, ks=k-half)
// frag f is 1 KB; lane l's 16B slot = A[m16*16 + (l&15)][kt*64+ks*32+(l>>4)*8 ..+8]
// One wave per fragment: reads 16 rows x 32 k (128B/row segments), writes 1 KB coalesced.
// ---------------------------------------------------------------------------
__global__ __launch_bounds__(256) void cvt_x_frag_kernel(
    const float* __restrict__ x, __bf16* __restrict__ xf) {
  int gw = (blockIdx.x * 256 + threadIdx.x) >> 6;   // fragment id, 0..65535
  int l  = threadIdx.x & 63;
  int m16 = gw >> 7;
  int rem = gw & 127;                                // kt*2 + ks
  int row = (m16 << 4) + (l & 15);
  int k   = (rem << 5) + ((l >> 4) << 3);            // kt*64 + ks*32 + (l>>4)*8
  const float* src = x + (size_t)row * K_DIM + k;
  f32x4 u = *(const f32x4*)src;
  f32x4 v = *(const f32x4*)(src + 4);
  bf16x8 o;
  o[0] = (__bf16)u[0]; o[1] = (__bf16)u[1]; o[2] = (__bf16)u[2]; o[3] = (__bf16)u[3];
  o[4] = (__bf16)v[0]; o[5] = (__bf16)v[1]; o[6] = (__bf16)v[2]; o[7] = (__bf16)v[3];
  *(bf16x8*)(xf + ((size_t)gw << 9) + (l << 3)) = o;
}

// ---------------------------------------------------------------------------
// 256x256 bf16 GEMM (R9): A-fragments DIRECT FROM GLOBAL (fragment-major,
// L1/L2-served, coalesced b128 per lane); only B staged in LDS (64 KiB dbuf,
// chunk-XOR swizzle, conflict-free 16x16 read pattern). 2 phases per K-tile,
// 2 barriers/tile. No manual in-loop vmcnt: compiler's FIFO wait for
// A-fragment consumption auto-drains older B-stages (>=2 phases); phase-end
// lgkmcnt(0)+barrier makes staging collective and closes ds_read/DMA WAR.
// P1(t): MMA quads (0,0),(0,1); stage Bh0(t+2); load a1(t).
// P2(t): MMA quads (1,1),(1,0); stage Bh1(t+2); load a0(t+1); ds_read b(t+1).
// ---------------------------------------------------------------------------
__global__ __launch_bounds__(512, 2) void anyprec_gemm_kernel(
    const __bf16* __restrict__ Af,  // fragment-major A
    const __bf16* __restrict__ B,   // N x K bf16
    const float* __restrict__ bias,
    float* __restrict__ C) {
  __shared__ __bf16 lds[2][2][128 * 64];   // [buf][half][128x64] = 65536 B

  // XCD-aware bijective swizzle (512 wgs, 512%8==0)
  int bid = blockIdx.x;
  int swz = (bid & 7) * 64 + (bid >> 3);
  int mb = swz >> 4;    // 32 m-tiles
  int nb = swz & 15;    // 16 n-tiles

  const int tid  = threadIdx.x;
  const int lane = tid & 63;
  const int wid  = tid >> 6;
  const int wr   = wid >> 2;   // 0..1
  const int wc   = wid & 3;    // 0..3

  // B staging
  const char* gB = (const char*)B + (size_t)nb * 256 * KB2;
  const size_t gro0 = (size_t)(tid >> 3) * KB2;
  const size_t gro1 = gro0 + (size_t)64 * KB2;
  const int    scx  = (((tid & 7) ^ ((tid >> 3) & 7)) << 4);
  const int    lt0  = tid * 16;
  const int    lt1  = tid * 16 + 8192;

  // B LDS read offsets (16x16 conflict-free pattern)
  const int boff0 = (wc * 32 + (lane & 15)) * 128;
  const int kko0  = (((lane >> 4)) ^ (lane & 7)) << 4;
  const int kko1  = ((4 + (lane >> 4)) ^ (lane & 7)) << 4;

  // A fragment-major base: frag(m16,kt,ks) at (m16*128 + kt*2 + ks)*1024
  const char* pA = (const char*)Af +
                   (size_t)(mb * 16 + wr * 4) * 131072 + (size_t)lane * 16;

  f32x4 acc[2][2][4][2];
#pragma unroll
  for (int qm = 0; qm < 2; ++qm)
#pragma unroll
    for (int qn = 0; qn < 2; ++qn)
#pragma unroll
      for (int mf = 0; mf < 4; ++mf)
#pragma unroll
        for (int nf = 0; nf < 2; ++nf) acc[qm][qn][mf][nf] = (f32x4)0.0f;

  bf16x8 a0[4][2], a1[4][2], b0[2][2], b1[2][2];

#define STAGEB(h, buf, t) {                                                \
    char* lb_ = (char*)&lds[buf][h][0];                                    \
    const char* gb_ = gB + (size_t)(h) * 128 * KB2 + (size_t)(t) * 128;    \
    GLD_LDS16(gb_ + gro0 + scx, lb_ + lt0);                                \
    GLD_LDS16(gb_ + gro1 + scx, lb_ + lt1); }

#define LDAG(dst, qm, t) {                                                 \
    const char* p_ = pA + (size_t)(qm) * 1048576 + (size_t)(t) * 2048;     \
    _Pragma("unroll")                                                      \
    for (int mf = 0; mf < 4; ++mf) {                                       \
      dst[mf][0] = *(const bf16x8*)(p_ + mf * 131072);                     \
      dst[mf][1] = *(const bf16x8*)(p_ + mf * 131072 + 1024); } }

#define LDBL(dst, qn, buf) {                                               \
    const char* p_ = (const char*)&lds[buf][qn][0] + boff0;                \
    _Pragma("unroll")                                                      \
    for (int nf = 0; nf < 2; ++nf) {                                       \
      dst[nf][0] = *(const bf16x8*)(p_ + nf * 2048 + kko0);                \
      dst[nf][1] = *(const bf16x8*)(p_ + nf * 2048 + kko1); } }

#define MMA(qm, qn, aa, bb) {                                              \
    _Pragma("unroll")                                                      \
    for (int mf = 0; mf < 4; ++mf)                                         \
      _Pragma("unroll")                                                    \
      for (int nf = 0; nf < 2; ++nf) {                                     \
        acc[qm][qn][mf][nf] = __builtin_amdgcn_mfma_f32_16x16x32_bf16(     \
            aa[mf][0], bb[nf][0], acc[qm][qn][mf][nf], 0, 0, 0);           \
        acc[qm][qn][mf][nf] = __builtin_amdgcn_mfma_f32_16x16x32_bf16(     \
            aa[mf][1], bb[nf][1], acc[qm][qn][mf][nf], 0, 0, 0); } }

#define PRIO1 __builtin_amdgcn_s_setprio(1);
#define PRIO0 __builtin_amdgcn_s_setprio(0);
#define BAR   __builtin_amdgcn_s_barrier();
#define SBAR  __builtin_amdgcn_sched_barrier(0);
#define LGKM0 asm volatile("s_waitcnt lgkmcnt(0)" ::: "memory");

  // ---- prologue: stage B(0)->buf0, B(1)->buf1; load a0(0); cert B(0)
  STAGEB(0, 0, 0); STAGEB(1, 0, 0);
  STAGEB(0, 1, 1); STAGEB(1, 1, 1);
  LDAG(a0, 0, 0);
  asm volatile("s_waitcnt vmcnt(12)" ::: "memory");  // B(0)=oldest 4 of 16 done
  BAR;                                               // collective
  LDBL(b0, 0, 0); LDBL(b1, 1, 0);
  LGKM0; BAR;   // reads drained before loop's first STAGE overwrites buf0 h0

  // ---- main loop: t = 0..61 (stages target t+2 <= 63), buf = t&1
  for (int t = 0; t < 62; ++t) {
    const int bcur = t & 1, bnxt = (t + 1) & 1;
    // P1(t)
    STAGEB(0, bcur, t + 2);
    LDAG(a1, 1, t);
    SBAR;
    PRIO1; MMA(0, 0, a0, b0); MMA(0, 1, a0, b1); PRIO0;
    LGKM0; BAR;
    // P2(t)
    STAGEB(1, bcur, t + 2);
    LDAG(a0, 0, t + 1);
    SBAR;
    PRIO1; MMA(1, 1, a1, b1); LDBL(b1, 1, bnxt);
    MMA(1, 0, a1, b0); LDBL(b0, 0, bnxt); PRIO0;
    LGKM0; BAR;
  }

  // ---- t = 62 (no stages; B(63) already staged at t=61)
  LDAG(a1, 1, 62);
  SBAR;
  PRIO1; MMA(0, 0, a0, b0); MMA(0, 1, a0, b1); PRIO0;
  LGKM0; BAR;
  LDAG(a0, 0, 63);
  SBAR;
  PRIO1; MMA(1, 1, a1, b1); LDBL(b1, 1, 1);
  MMA(1, 0, a1, b0); LDBL(b0, 0, 1); PRIO0;
  LGKM0; BAR;
  // ---- t = 63
  LDAG(a1, 1, 63);
  SBAR;
  PRIO1; MMA(0, 0, a0, b0); MMA(0, 1, a0, b1);
  MMA(1, 1, a1, b1); MMA(1, 0, a1, b0); PRIO0;

  // ---- epilogue: C/D layout col=lane&15, row=(lane>>4)*4+j
  const int cL = lane & 15;
  const int rL = (lane >> 4) * 4;
#pragma unroll
  for (int qn = 0; qn < 2; ++qn)
#pragma unroll
    for (int nf = 0; nf < 2; ++nf) {
      int col = nb * 256 + qn * 128 + wc * 32 + nf * 16 + cL;
      float bv = bias[col];
#pragma unroll
      for (int qm = 0; qm < 2; ++qm)
#pragma unroll
        for (int mf = 0; mf < 4; ++mf) {
          int row0 = mb * 256 + qm * 128 + wr * 64 + mf * 16 + rL;
#pragma unroll
          for (int j = 0; j < 4; ++j)
            C[(size_t)(row0 + j) * N_DIM + col] = acc[qm][qn][mf][nf][j] + bv;
        }
    }
#undef STAGEB
#undef LDAG
#undef LDBL
#undef MMA
#undef PRIO1
#undef PRIO0
#undef BAR
#undef SBAR
#undef LGKM0
}

extern "C" void kernel_launch(void* const* d_in, const int* in_sizes, int n_in,
                              void* d_out, int out_size, void* d_ws, size_t ws_size,
                              hipStream_t stream) {
  const float* x    = (const float*)d_in[0];
  const int*   qw   = (const int*)d_in[1];
  const float* lut  = (const float*)d_in[2];
  const float* bias = (const float*)d_in[3];

  __bf16* Wb = (__bf16*)d_ws;                                   // 32 MB
  __bf16* Xf = (__bf16*)((char*)d_ws + (size_t)N_DIM * K_DIM * 2);  // 64 MB

  {
    int total = N_DIM * (K_DIM / 32);
    anyprec_dequant_kernel<<<total / 256, 256, 0, stream>>>(qw, lut, Wb);
  }
  {
    // 65536 fragments, one wave each, 4 waves/block
    cvt_x_frag_kernel<<<16384, 256, 0, stream>>>(x, Xf);
  }
  {
    dim3 grid((M_DIM / 256) * (N_DIM / 256));  // 32*16 = 512
    anyprec_gemm_kernel<<<grid, 512, 0, stream>>>(Xf, Wb, bias, (float*)d_out);
  }
}

// Round 10
// 275.417 us; speedup vs baseline: 1.2408x; 1.2408x over previous
//
#include <hip/hip_runtime.h>
#include <hip/hip_bf16.h>
#include <stdint.h>

#define M_DIM 8192   // 4*2048
#define N_DIM 4096   // OUT_FEATURES
#define K_DIM 4096   // IN_FEATURES
#define KB2   (K_DIM * 2)   // bytes per K-row

typedef __attribute__((ext_vector_type(8))) __bf16 bf16x8;
typedef __attribute__((ext_vector_type(4))) float  f32x4;

#define GLD_LDS16(gaddr, laddr)                                            \
  __builtin_amdgcn_global_load_lds(                                        \
      (const __attribute__((address_space(1))) uint32_t*)(gaddr),          \
      (__attribute__((address_space(3))) uint32_t*)(laddr), 16, 0, 0)

// ---------------------------------------------------------------------------
// Dequant: qweight (8, O, 128) int32 bit-planes + lut (O,16) -> Wb (O,K) bf16
// ---------------------------------------------------------------------------
__global__ __launch_bounds__(256) void anyprec_dequant_kernel(
    const int* __restrict__ q, const float* __restrict__ lut,
    __bf16* __restrict__ Wb) {
  int t = blockIdx.x * 256 + threadIdx.x;   // 0 .. O*128-1
  int o = t >> 7;
  int w = t & 127;
  const int PLANE = N_DIM * (K_DIM / 32);
  int base = o * (K_DIM / 32) + w;
  uint32_t q0 = (uint32_t)q[0 * PLANE + base];
  uint32_t q1 = (uint32_t)q[1 * PLANE + base];
  uint32_t q2 = (uint32_t)q[2 * PLANE + base];
  uint32_t q3 = (uint32_t)q[3 * PLANE + base];
  const float* lrow = lut + o * 16;

  __bf16 vals[32];
#pragma unroll
  for (int i = 0; i < 32; ++i) {
    uint32_t idx = ((q0 >> i) & 1u) | (((q1 >> i) & 1u) << 1) |
                   (((q2 >> i) & 1u) << 2) | (((q3 >> i) & 1u) << 3);
    vals[i] = (__bf16)lrow[idx];
  }
  bf16x8* dst = (bf16x8*)(Wb + (size_t)o * K_DIM + w * 32);
#pragma unroll
  for (int r = 0; r < 4; ++r) {
    bf16x8 v;
#pragma unroll
    for (int j = 0; j < 8; ++j) v[j] = vals[r * 8 + j];
    dst[r] = v;
  }
}

// ---------------------------------------------------------------------------
// x fp32 -> bf16
// ---------------------------------------------------------------------------
__global__ __launch_bounds__(256) void cvt_x_kernel(
    const float* __restrict__ x, __bf16* __restrict__ xb, int n8) {
  int t = blockIdx.x * 256 + threadIdx.x;
  if (t >= n8) return;
  f32x4 a = ((const f32x4*)x)[t * 2];
  f32x4 b = ((const f32x4*)x)[t * 2 + 1];
  bf16x8 v;
  v[0] = (__bf16)a[0]; v[1] = (__bf16)a[1]; v[2] = (__bf16)a[2]; v[3] = (__bf16)a[3];
  v[4] = (__bf16)b[0]; v[5] = (__bf16)b[1]; v[6] = (__bf16)b[2]; v[7] = (__bf16)b[3];
  ((bf16x8*)xb)[t] = v;
}

// ---------------------------------------------------------------------------
// 256x256 bf16 GEMM, R10: 2 phases per K-tile (2 barriers/tile, half of R8).
// 512 thr = 8 waves (2M x 4N), BK=64, LDS 128 KiB dbuf, 16x16x32 MFMA with
// conflict-free chunk-XOR pattern. Per phase: 32 MFMA + 12 ds_read_b128 +
// 2 half-tile stages (balanced). Collective certs: vmcnt(4) at end-P1 only
// (before barrier); lgkmcnt(0) before every barrier closes stage/read WAR.
//   P1(t): stage A0,B0(t+2); read b1(t),a1(t);  MMA(0,0) MMA(0,1)
//   P2(t): stage A1,B1(t+2); read a0,b0(t+1);   MMA(1,1) MMA(1,0)
// ---------------------------------------------------------------------------
__global__ __launch_bounds__(512, 2) void anyprec_gemm_kernel(
    const __bf16* __restrict__ A,   // M x K bf16
    const __bf16* __restrict__ B,   // N x K bf16
    const float* __restrict__ bias,
    float* __restrict__ C) {
  __shared__ __bf16 lds[2][2][2][128 * 64];   // 131072 B

  // XCD-aware bijective swizzle (512 wgs, 512%8==0)
  int bid = blockIdx.x;
  int swz = (bid & 7) * 64 + (bid >> 3);
  int mb = swz >> 4;    // 32 m-tiles
  int nb = swz & 15;    // 16 n-tiles

  const int tid  = threadIdx.x;
  const int lane = tid & 63;
  const int wid  = tid >> 6;
  const int wr   = wid >> 2;   // 0..1
  const int wc   = wid & 3;    // 0..3

  const char* gA = (const char*)A + (size_t)mb * 256 * KB2;
  const char* gB = (const char*)B + (size_t)nb * 256 * KB2;
  const size_t gro0 = (size_t)(tid >> 3) * KB2;       // row  = chunk>>3
  const size_t gro1 = gro0 + (size_t)64 * KB2;        // row + 64
  const int    scx  = (((tid & 7) ^ ((tid >> 3) & 7)) << 4);  // swizzled src chunk
  const int    lt0  = tid * 16;
  const int    lt1  = tid * 16 + 8192;

  const int aoff0 = (wr * 64 + (lane & 15)) * 128;
  const int boff0 = (wc * 32 + (lane & 15)) * 128;
  const int kko0  = (((lane >> 4)) ^ (lane & 7)) << 4;
  const int kko1  = ((4 + (lane >> 4)) ^ (lane & 7)) << 4;

  f32x4 acc[2][2][4][2];
#pragma unroll
  for (int qm = 0; qm < 2; ++qm)
#pragma unroll
    for (int qn = 0; qn < 2; ++qn)
#pragma unroll
      for (int mf = 0; mf < 4; ++mf)
#pragma unroll
        for (int nf = 0; nf < 2; ++nf) acc[qm][qn][mf][nf] = (f32x4)0.0f;

  bf16x8 a0[4][2], a1[4][2], b0[2][2], b1[2][2];

#define STAGE(mat, h, buf, t) {                                            \
    char* lb_ = (char*)&lds[buf][mat][h][0];                               \
    const char* gb_ = (mat ? gB : gA) + (size_t)(h) * 128 * KB2            \
                      + (size_t)(t) * 128;                                 \
    GLD_LDS16(gb_ + gro0 + scx, lb_ + lt0);                                \
    GLD_LDS16(gb_ + gro1 + scx, lb_ + lt1); }

#define LDA(dst, qm, buf) {                                                \
    const char* p_ = (const char*)&lds[buf][0][qm][0] + aoff0;             \
    _Pragma("unroll")                                                      \
    for (int mf = 0; mf < 4; ++mf) {                                       \
      dst[mf][0] = *(const bf16x8*)(p_ + mf * 2048 + kko0);                \
      dst[mf][1] = *(const bf16x8*)(p_ + mf * 2048 + kko1); } }

#define LDB(dst, qn, buf) {                                                \
    const char* p_ = (const char*)&lds[buf][1][qn][0] + boff0;             \
    _Pragma("unroll")                                                      \
    for (int nf = 0; nf < 2; ++nf) {                                       \
      dst[nf][0] = *(const bf16x8*)(p_ + nf * 2048 + kko0);                \
      dst[nf][1] = *(const bf16x8*)(p_ + nf * 2048 + kko1); } }

#define MMA(qm, qn, aa, bb) {                                              \
    _Pragma("unroll")                                                      \
    for (int mf = 0; mf < 4; ++mf)                                         \
      _Pragma("unroll")                                                    \
      for (int nf = 0; nf < 2; ++nf) {                                     \
        acc[qm][qn][mf][nf] = __builtin_amdgcn_mfma_f32_16x16x32_bf16(     \
            aa[mf][0], bb[nf][0], acc[qm][qn][mf][nf], 0, 0, 0);           \
        acc[qm][qn][mf][nf] = __builtin_amdgcn_mfma_f32_16x16x32_bf16(     \
            aa[mf][1], bb[nf][1], acc[qm][qn][mf][nf], 0, 0, 0); } }

#define PRIO1 __builtin_amdgcn_s_setprio(1);
#define PRIO0 __builtin_amdgcn_s_setprio(0);
#define BAR   __builtin_amdgcn_s_barrier();
#define LGKM0 asm volatile("s_waitcnt lgkmcnt(0)" ::: "memory");
#define VMC(n) asm volatile("s_waitcnt vmcnt(" #n ")" ::: "memory");

  // ---- prologue: stage tiles 0 and 1 fully; collective-cert tile 0
  STAGE(0, 0, 0, 0);  // A0(0)
  STAGE(1, 0, 0, 0);  // B0(0)
  STAGE(0, 1, 0, 0);  // A1(0)
  STAGE(1, 1, 0, 0);  // B1(0)
  STAGE(0, 0, 1, 1);  // A0(1)
  STAGE(1, 0, 1, 1);  // B0(1)
  STAGE(0, 1, 1, 1);  // A1(1)
  STAGE(1, 1, 1, 1);  // B1(1)
  VMC(8); BAR;        // tile0 certified for ALL waves (8 newest = tile1 in flight)
  LDA(a0, 0, 0); LDB(b0, 0, 0);

  // ---- main loop: t = 0..61, buf c = t&1; stages target t+2 (buf c)
  for (int t = 0; t < 62; ++t) {
    const int c = t & 1, n = (t + 1) & 1;
    // P1(t): MMA quads (0,0),(0,1); read b1,a1(t); stage A0,B0(t+2)
    STAGE(0, 0, c, t + 2);
    STAGE(1, 0, c, t + 2);
    PRIO1; LDB(b1, 1, c); LDA(a1, 1, c);
    MMA(0, 0, a0, b0); MMA(0, 1, a0, b1); PRIO0;
    LGKM0; VMC(4); BAR;   // cert tile t+1 (collective after barrier)
    // P2(t): MMA quads (1,1),(1,0); read a0,b0(t+1); stage A1,B1(t+2)
    STAGE(0, 1, c, t + 2);
    STAGE(1, 1, c, t + 2);
    PRIO1; LDA(a0, 0, n); MMA(1, 1, a1, b1);
    MMA(1, 0, a1, b0); LDB(b0, 0, n); PRIO0;
    LGKM0; BAR;
  }

  // ---- tail: t = 62 (buf0), t = 63 (buf1); no more stages
  // P1(62)
  PRIO1; LDB(b1, 1, 0); LDA(a1, 1, 0);
  MMA(0, 0, a0, b0); MMA(0, 1, a0, b1); PRIO0;
  LGKM0; VMC(0); BAR;   // tile 63 fully certified
  // P2(62)
  PRIO1; LDA(a0, 0, 1); MMA(1, 1, a1, b1);
  MMA(1, 0, a1, b0); LDB(b0, 0, 1); PRIO0;
  LGKM0; BAR;
  // P1(63)
  PRIO1; LDB(b1, 1, 1); LDA(a1, 1, 1);
  MMA(0, 0, a0, b0); MMA(0, 1, a0, b1); PRIO0;
  // P2(63)
  MMA(1, 1, a1, b1);
  MMA(1, 0, a1, b0);

  // ---- epilogue: C/D layout col=lane&15, row=(lane>>4)*4+j
  const int cL = lane & 15;
  const int rL = (lane >> 4) * 4;
#pragma unroll
  for (int qn = 0; qn < 2; ++qn)
#pragma unroll
    for (int nf = 0; nf < 2; ++nf) {
      int col = nb * 256 + qn * 128 + wc * 32 + nf * 16 + cL;
      float bv = bias[col];
#pragma unroll
      for (int qm = 0; qm < 2; ++qm)
#pragma unroll
        for (int mf = 0; mf < 4; ++mf) {
          int row0 = mb * 256 + qm * 128 + wr * 64 + mf * 16 + rL;
#pragma unroll
          for (int j = 0; j < 4; ++j)
            C[(size_t)(row0 + j) * N_DIM + col] = acc[qm][qn][mf][nf][j] + bv;
        }
    }
#undef STAGE
#undef LDA
#undef LDB
#undef MMA
#undef PRIO1
#undef PRIO0
#undef BAR
#undef LGKM0
#undef VMC
}

extern "C" void kernel_launch(void* const* d_in, const int* in_sizes, int n_in,
                              void* d_out, int out_size, void* d_ws, size_t ws_size,
                              hipStream_t stream) {
  const float* x    = (const float*)d_in[0];
  const int*   qw   = (const int*)d_in[1];
  const float* lut  = (const float*)d_in[2];
  const float* bias = (const float*)d_in[3];

  __bf16* Wb = (__bf16*)d_ws;
  __bf16* Xb = (__bf16*)((char*)d_ws + (size_t)N_DIM * K_DIM * 2);

  {
    int total = N_DIM * (K_DIM / 32);
    anyprec_dequant_kernel<<<total / 256, 256, 0, stream>>>(qw, lut, Wb);
  }
  {
    int n8 = (M_DIM * K_DIM) / 8;
    cvt_x_kernel<<<(n8 + 255) / 256, 256, 0, stream>>>(x, Xb, n8);
  }
  {
    dim3 grid((M_DIM / 256) * (N_DIM / 256));  // 32*16 = 512
    anyprec_gemm_kernel<<<grid, 512, 0, stream>>>(Xb, Wb, bias, (float*)d_out);
  }
}